// Round 9
// baseline (543.040 us; speedup 1.0000x reference)
//
#include <hip/hip_runtime.h>

typedef __bf16 bf16;
typedef __bf16 bf16x4 __attribute__((ext_vector_type(4)));
typedef __bf16 bf16x8 __attribute__((ext_vector_type(8)));
typedef float  fx4    __attribute__((ext_vector_type(4)));

#define MFMA16(a, b, c) __builtin_amdgcn_mfma_f32_16x16x32_bf16((a), (b), (c), 0, 0, 0)

// B=4, N=2048, E=768, H=8, D=96; M = B*N = 8192. User tensors fp32, out fp32.

// ---------------------------------------------------------------------------
// x (fp32) -> bf16, 4 elems/thread.
// ---------------------------------------------------------------------------
__global__ __launch_bounds__(256)
void cvt_x_kernel(const float* __restrict__ x, bf16* __restrict__ xb) {
  const int i = (blockIdx.x * 256 + threadIdx.x) * 4;
  float4 v = *(const float4*)&x[i];
  bf16x4 o;
  o[0] = (bf16)v.x; o[1] = (bf16)v.y; o[2] = (bf16)v.z; o[3] = (bf16)v.w;
  *(bf16x4*)&xb[i] = o;
}

// ---------------------------------------------------------------------------
// Fused QKV GEMM (round-7 proven). blockIdx.x: 0-5 Q, 6-11 K, 12-17 V
// (V transposed out). 1152 blocks. Tile 128x128, BK=32, 4 waves, 4x4 MFMAs.
// ---------------------------------------------------------------------------
__global__ __launch_bounds__(256)
void gemm_qkv(const bf16* __restrict__ A,
              const float* __restrict__ Wq, const float* __restrict__ Wk,
              const float* __restrict__ Wv,
              const float* __restrict__ bq, const float* __restrict__ bk,
              const float* __restrict__ bv,
              bf16* __restrict__ Qo, bf16* __restrict__ Ko,
              bf16* __restrict__ Vto) {
  constexpr int K = 768;
  __shared__ __align__(16) bf16 As[128 * 32];
  __shared__ __align__(16) bf16 Bs[128 * 32];

  const int tid  = threadIdx.x;
  const int wave = tid >> 6;
  const int lane = tid & 63;
  const int l15  = lane & 15;
  const int q4   = lane >> 4;
  const int wr   = wave >> 1;
  const int wc   = wave & 1;
  const int sel  = blockIdx.x / 6;
  const int cb0  = (blockIdx.x % 6) * 128;
  const int rb0  = blockIdx.y * 128;

  const float* W   = (sel == 0) ? Wq : (sel == 1) ? Wk : Wv;
  const float* bia = (sel == 0) ? bq : (sel == 1) ? bk : bv;

  fx4 acc[4][4];
#pragma unroll
  for (int i = 0; i < 4; i++)
#pragma unroll
    for (int j = 0; j < 4; j++) acc[i][j] = (fx4){0.f, 0.f, 0.f, 0.f};

  for (int k0 = 0; k0 < K; k0 += 32) {
    for (int c = tid; c < 512; c += 256) {
      const int row = c >> 2;
      const int kc  = (c & 3) << 3;
      *(uint4*)&As[row * 32 + kc] =
          *(const uint4*)&A[(size_t)(rb0 + row) * K + k0 + kc];
      const float* sb = W + (size_t)(cb0 + row) * K + k0 + kc;
      bf16x8 pb;
#pragma unroll
      for (int t = 0; t < 8; t++) pb[t] = (bf16)sb[t];
      *(bf16x8*)&Bs[row * 32 + kc] = pb;
    }
    __syncthreads();

    bf16x8 a[4], b[4];
#pragma unroll
    for (int i = 0; i < 4; i++)
      a[i] = *(const bf16x8*)&As[(wr * 64 + i * 16 + l15) * 32 + q4 * 8];
#pragma unroll
    for (int j = 0; j < 4; j++)
      b[j] = *(const bf16x8*)&Bs[(wc * 64 + j * 16 + l15) * 32 + q4 * 8];
#pragma unroll
    for (int i = 0; i < 4; i++)
#pragma unroll
      for (int j = 0; j < 4; j++)
        acc[i][j] = MFMA16(a[i], b[j], acc[i][j]);
    __syncthreads();
  }

  const int cb = cb0 + wc * 64;
  const int rb = rb0 + wr * 64;
  bf16* Co = (sel == 0) ? Qo : Ko;
#pragma unroll
  for (int j = 0; j < 4; j++) {
    const int o  = cb + j * 16 + l15;
    const float bj = bia[o];
#pragma unroll
    for (int i = 0; i < 4; i++) {
      const int r0 = rb + i * 16 + q4 * 4;
      if (sel == 2) {
        const int bb = r0 >> 11;
        const int n0 = r0 & 2047;
        bf16x4 pk;
#pragma unroll
        for (int r = 0; r < 4; r++) pk[r] = (bf16)(acc[i][j][r] + bj);
        *(bf16x4*)&Vto[((size_t)(bb * 768 + o)) * 2048 + n0] = pk;
      } else {
#pragma unroll
        for (int r = 0; r < 4; r++)
          Co[(size_t)(r0 + r) * 768 + o] = (bf16)(acc[i][j][r] + bj);
      }
    }
  }
}

// ---------------------------------------------------------------------------
// Output projection: out[M,768] fp32 = AO bf16 @ Wo^T + bo (round-7 proven).
// ---------------------------------------------------------------------------
__global__ __launch_bounds__(256)
void gemm_o(const bf16* __restrict__ A, const float* __restrict__ W,
            const float* __restrict__ bias, float* __restrict__ C) {
  constexpr int K = 768;
  __shared__ __align__(16) bf16 As[128 * 32];
  __shared__ __align__(16) bf16 Bs[128 * 32];

  const int tid  = threadIdx.x;
  const int wave = tid >> 6;
  const int lane = tid & 63;
  const int l15  = lane & 15;
  const int q4   = lane >> 4;
  const int wr   = wave >> 1;
  const int wc   = wave & 1;
  const int rb0  = blockIdx.y * 128;
  const int cb0  = blockIdx.x * 128;

  fx4 acc[4][4];
#pragma unroll
  for (int i = 0; i < 4; i++)
#pragma unroll
    for (int j = 0; j < 4; j++) acc[i][j] = (fx4){0.f, 0.f, 0.f, 0.f};

  for (int k0 = 0; k0 < K; k0 += 32) {
    for (int c = tid; c < 512; c += 256) {
      const int row = c >> 2;
      const int kc  = (c & 3) << 3;
      *(uint4*)&As[row * 32 + kc] =
          *(const uint4*)&A[(size_t)(rb0 + row) * K + k0 + kc];
      const float* sb = W + (size_t)(cb0 + row) * K + k0 + kc;
      bf16x8 pb;
#pragma unroll
      for (int t = 0; t < 8; t++) pb[t] = (bf16)sb[t];
      *(bf16x8*)&Bs[row * 32 + kc] = pb;
    }
    __syncthreads();

    bf16x8 a[4], b[4];
#pragma unroll
    for (int i = 0; i < 4; i++)
      a[i] = *(const bf16x8*)&As[(wr * 64 + i * 16 + l15) * 32 + q4 * 8];
#pragma unroll
    for (int j = 0; j < 4; j++)
      b[j] = *(const bf16x8*)&Bs[(wc * 64 + j * 16 + l15) * 32 + q4 * 8];
#pragma unroll
    for (int i = 0; i < 4; i++)
#pragma unroll
      for (int j = 0; j < 4; j++)
        acc[i][j] = MFMA16(a[i], b[j], acc[i][j]);
    __syncthreads();
  }

  const int cb = cb0 + wc * 64;
  const int rb = rb0 + wr * 64;
#pragma unroll
  for (int j = 0; j < 4; j++) {
    const int o  = cb + j * 16 + l15;
    const float bj = bias[o];
#pragma unroll
    for (int i = 0; i < 4; i++) {
      const int r0 = rb + i * 16 + q4 * 4;
#pragma unroll
      for (int r = 0; r < 4; r++)
        C[(size_t)(r0 + r) * 768 + o] = acc[i][j][r] + bj;
    }
  }
}

// ---------------------------------------------------------------------------
// Attention, softmax over HEADS (dim=1), / sqrt(768).
// In-register cross-head softmax + fully batched loads (merges the round-6
// structure with the round-7 fix for its load serialization):
//  - TQ=16: ALL 24 Q fragments (8 heads x 3 chunks) live in registers.
//  - QK phase: wave w owns keys [kt*128 + w*16, +16); computes E for all 8
//    heads into 8 accumulators -> each lane holds E_h(q,k) for all h at one
//    (q,k) -> softmax over h is pure VALU. No Ebuf, no softmax barriers.
//  - P goes through LDS only for the C->A layout transpose (32 b16 writes),
//    2 barriers per TK=128 tile = 32 barriers total (vs 128 in round 7).
//  - PV phase: wave w = head w, V loads batched in 2 groups of 12.
// Grid = 4*128 = 512 blocks, 512 thr. VGPR ~220 -> 1 block/CU (2 passes).
// AO aliases Q: block reads only its own 16 Q rows (regs, before loop),
// writes only those rows after. Pbuf stride 136: PV b128 reads 2-way (free).
// ---------------------------------------------------------------------------
__global__ __launch_bounds__(512, 2)
void attn_kernel(const bf16* Q, const bf16* __restrict__ Kb,
                 const bf16* __restrict__ Vt, bf16* AO) {
  constexpr int PS = 136;
  __shared__ __align__(16) bf16 Pbuf[8 * 16 * PS];  // [h][q][k] 34.8 KB

  const int tid  = threadIdx.x;
  const int w    = tid >> 6;      // wave = k-slice (QK) / head (PV)
  const int lane = tid & 63;
  const int l15  = lane & 15;
  const int q4   = lane >> 4;
  const int b    = blockIdx.x >> 7;
  const int qt   = blockIdx.x & 127;
  const int qrow0 = b * 2048 + qt * 16;

  // All Q fragments in registers: A[m=q=l15][kk=q4*8+t], 8 heads x 3 chunks.
  bf16x8 aq[8][3];
#pragma unroll
  for (int h = 0; h < 8; h++)
#pragma unroll
    for (int c = 0; c < 3; c++)
      aq[h][c] = *(const bf16x8*)
          &Q[(size_t)(qrow0 + l15) * 768 + h * 96 + c * 32 + q4 * 8];

  fx4 o[6];
#pragma unroll
  for (int j = 0; j < 6; j++) o[j] = (fx4){0.f, 0.f, 0.f, 0.f};

  // Per-lane base pointers.
  const bf16* Kp0 = Kb + (size_t)(b * 2048 + w * 16 + l15) * 768 + q4 * 8;
  const bf16* Vp0 = Vt + (size_t)((b * 8 + w) * 96 + l15) * 2048 + q4 * 8;

  for (int kt = 0; kt < 16; kt++) {
    const bf16* Kp = Kp0 + (size_t)kt * 128 * 768;

    // ---- QK for all 8 heads; K loads batched in 2 groups of 12.
    fx4 e[8];
#pragma unroll
    for (int h = 0; h < 8; h++) e[h] = (fx4){0.f, 0.f, 0.f, 0.f};
#pragma unroll
    for (int g = 0; g < 2; g++) {
      bf16x8 bk[4][3];
#pragma unroll
      for (int hh = 0; hh < 4; hh++)
#pragma unroll
        for (int c = 0; c < 3; c++)
          bk[hh][c] = *(const bf16x8*)(Kp + (g * 4 + hh) * 96 + c * 32);
#pragma unroll
      for (int hh = 0; hh < 4; hh++)
#pragma unroll
        for (int c = 0; c < 3; c++)
          e[g * 4 + hh] = MFMA16(aq[g * 4 + hh][c], bk[hh][c], e[g * 4 + hh]);
    }

    // ---- V loads, group 1 (c2=0,1): in flight across softmax + barrier.
    bf16x8 bv0[2][6];
#pragma unroll
    for (int c2 = 0; c2 < 2; c2++)
#pragma unroll
      for (int j2 = 0; j2 < 6; j2++)
        bv0[c2][j2] = *(const bf16x8*)
            (Vp0 + (size_t)(j2 * 16) * 2048 + kt * 128 + c2 * 32);

    // ---- In-register softmax over heads; write P (bf16) to LDS transpose.
#pragma unroll
    for (int r = 0; r < 4; r++) {
      float m = e[0][r];
#pragma unroll
      for (int h = 1; h < 8; h++) m = fmaxf(m, e[h][r]);
      float p[8], s = 0.f;
#pragma unroll
      for (int h = 0; h < 8; h++) { p[h] = __expf(e[h][r] - m); s += p[h]; }
      const float inv = 1.0f / (s * 27.712812921102035f);  // / sqrt(768)
#pragma unroll
      for (int h = 0; h < 8; h++)
        Pbuf[(h * 16 + q4 * 4 + r) * PS + w * 16 + l15] = (bf16)(p[h] * inv);
    }
    __syncthreads();

    // ---- PV: wave = head w. O[16q x 96d] += P[16 x 128] @ V[128 x 96].
    bf16x8 ap[4];
#pragma unroll
    for (int c2 = 0; c2 < 4; c2++)
      ap[c2] = *(const bf16x8*)&Pbuf[(w * 16 + l15) * PS + c2 * 32 + q4 * 8];

    // V loads, group 2 (c2=2,3).
    bf16x8 bv1[2][6];
#pragma unroll
    for (int c2 = 0; c2 < 2; c2++)
#pragma unroll
      for (int j2 = 0; j2 < 6; j2++)
        bv1[c2][j2] = *(const bf16x8*)
            (Vp0 + (size_t)(j2 * 16) * 2048 + kt * 128 + (c2 + 2) * 32);

#pragma unroll
    for (int c2 = 0; c2 < 2; c2++)
#pragma unroll
      for (int j2 = 0; j2 < 6; j2++)
        o[j2] = MFMA16(ap[c2], bv0[c2][j2], o[j2]);
#pragma unroll
    for (int c2 = 0; c2 < 2; c2++)
#pragma unroll
      for (int j2 = 0; j2 < 6; j2++)
        o[j2] = MFMA16(ap[c2 + 2], bv1[c2][j2], o[j2]);
    __syncthreads();  // protect Pbuf rewrite next iteration
  }

  // Write AO[qrow0 + q][w*96 + d]
#pragma unroll
  for (int j2 = 0; j2 < 6; j2++)
#pragma unroll
    for (int r = 0; r < 4; r++)
      AO[(size_t)(qrow0 + q4 * 4 + r) * 768 + w * 96 + j2 * 16 + l15] =
          (bf16)(o[j2][r]);
}

// ---------------------------------------------------------------------------
// Memory plan (round-7 proven): d_out = xb + Kw (both dead before gemm_o
// overwrites d_out fp32). ws = Q + Vt (25.2 MB). AO aliases Q.
// ---------------------------------------------------------------------------
extern "C" void kernel_launch(void* const* d_in, const int* in_sizes, int n_in,
                              void* d_out, int out_size, void* d_ws,
                              size_t ws_size, hipStream_t stream) {
  const float* x  = (const float*)d_in[0];
  const float* Wq = (const float*)d_in[1];
  const float* bq = (const float*)d_in[2];
  const float* Wk = (const float*)d_in[3];
  const float* bk = (const float*)d_in[4];
  const float* Wv = (const float*)d_in[5];
  const float* bv = (const float*)d_in[6];
  const float* Wo = (const float*)d_in[7];
  const float* bo = (const float*)d_in[8];

  const size_t MN = (size_t)8192 * 768;
  bf16* xb = (bf16*)d_out;
  bf16* Kw = xb + MN;
  bf16* Q  = (bf16*)d_ws;
  bf16* Vt = Q + MN;
  bf16* AO = Q;  // aliases Q

  cvt_x_kernel<<<6144, 256, 0, stream>>>(x, xb);
  dim3 qkvgrid(18, 64);
  gemm_qkv<<<qkvgrid, 256, 0, stream>>>(xb, Wq, Wk, Wv, bq, bk, bv, Q, Kw, Vt);
  attn_kernel<<<512, 512, 0, stream>>>(Q, Kw, Vt, AO);
  dim3 ogrid(6, 64);
  gemm_o<<<ogrid, 256, 0, stream>>>(AO, Wo, bo, (float*)d_out);
}

// Round 10
// 385.551 us; speedup vs baseline: 1.4085x; 1.4085x over previous
//
#include <hip/hip_runtime.h>

typedef __bf16 bf16;
typedef __bf16 bf16x4 __attribute__((ext_vector_type(4)));
typedef __bf16 bf16x8 __attribute__((ext_vector_type(8)));
typedef float  fx4    __attribute__((ext_vector_type(4)));

#define MFMA16(a, b, c) __builtin_amdgcn_mfma_f32_16x16x32_bf16((a), (b), (c), 0, 0, 0)

// B=4, N=2048, E=768, H=8, D=96; M = B*N = 8192. User tensors fp32, out fp32.

// ---------------------------------------------------------------------------
// x (fp32) -> bf16, 4 elems/thread.
// ---------------------------------------------------------------------------
__global__ __launch_bounds__(256)
void cvt_x_kernel(const float* __restrict__ x, bf16* __restrict__ xb) {
  const int i = (blockIdx.x * 256 + threadIdx.x) * 4;
  float4 v = *(const float4*)&x[i];
  bf16x4 o;
  o[0] = (bf16)v.x; o[1] = (bf16)v.y; o[2] = (bf16)v.z; o[3] = (bf16)v.w;
  *(bf16x4*)&xb[i] = o;
}

// ---------------------------------------------------------------------------
// Fused QKV GEMM (round-7 proven). blockIdx.x: 0-5 Q, 6-11 K, 12-17 V
// (V transposed out). 1152 blocks. Tile 128x128, BK=32, 4 waves, 4x4 MFMAs.
// ---------------------------------------------------------------------------
__global__ __launch_bounds__(256)
void gemm_qkv(const bf16* __restrict__ A,
              const float* __restrict__ Wq, const float* __restrict__ Wk,
              const float* __restrict__ Wv,
              const float* __restrict__ bq, const float* __restrict__ bk,
              const float* __restrict__ bv,
              bf16* __restrict__ Qo, bf16* __restrict__ Ko,
              bf16* __restrict__ Vto) {
  constexpr int K = 768;
  __shared__ __align__(16) bf16 As[128 * 32];
  __shared__ __align__(16) bf16 Bs[128 * 32];

  const int tid  = threadIdx.x;
  const int wave = tid >> 6;
  const int lane = tid & 63;
  const int l15  = lane & 15;
  const int q4   = lane >> 4;
  const int wr   = wave >> 1;
  const int wc   = wave & 1;
  const int sel  = blockIdx.x / 6;
  const int cb0  = (blockIdx.x % 6) * 128;
  const int rb0  = blockIdx.y * 128;

  const float* W   = (sel == 0) ? Wq : (sel == 1) ? Wk : Wv;
  const float* bia = (sel == 0) ? bq : (sel == 1) ? bk : bv;

  fx4 acc[4][4];
#pragma unroll
  for (int i = 0; i < 4; i++)
#pragma unroll
    for (int j = 0; j < 4; j++) acc[i][j] = (fx4){0.f, 0.f, 0.f, 0.f};

  for (int k0 = 0; k0 < K; k0 += 32) {
    for (int c = tid; c < 512; c += 256) {
      const int row = c >> 2;
      const int kc  = (c & 3) << 3;
      *(uint4*)&As[row * 32 + kc] =
          *(const uint4*)&A[(size_t)(rb0 + row) * K + k0 + kc];
      const float* sb = W + (size_t)(cb0 + row) * K + k0 + kc;
      bf16x8 pb;
#pragma unroll
      for (int t = 0; t < 8; t++) pb[t] = (bf16)sb[t];
      *(bf16x8*)&Bs[row * 32 + kc] = pb;
    }
    __syncthreads();

    bf16x8 a[4], b[4];
#pragma unroll
    for (int i = 0; i < 4; i++)
      a[i] = *(const bf16x8*)&As[(wr * 64 + i * 16 + l15) * 32 + q4 * 8];
#pragma unroll
    for (int j = 0; j < 4; j++)
      b[j] = *(const bf16x8*)&Bs[(wc * 64 + j * 16 + l15) * 32 + q4 * 8];
#pragma unroll
    for (int i = 0; i < 4; i++)
#pragma unroll
      for (int j = 0; j < 4; j++)
        acc[i][j] = MFMA16(a[i], b[j], acc[i][j]);
    __syncthreads();
  }

  const int cb = cb0 + wc * 64;
  const int rb = rb0 + wr * 64;
  bf16* Co = (sel == 0) ? Qo : Ko;
#pragma unroll
  for (int j = 0; j < 4; j++) {
    const int o  = cb + j * 16 + l15;
    const float bj = bia[o];
#pragma unroll
    for (int i = 0; i < 4; i++) {
      const int r0 = rb + i * 16 + q4 * 4;
      if (sel == 2) {
        const int bb = r0 >> 11;
        const int n0 = r0 & 2047;
        bf16x4 pk;
#pragma unroll
        for (int r = 0; r < 4; r++) pk[r] = (bf16)(acc[i][j][r] + bj);
        *(bf16x4*)&Vto[((size_t)(bb * 768 + o)) * 2048 + n0] = pk;
      } else {
#pragma unroll
        for (int r = 0; r < 4; r++)
          Co[(size_t)(r0 + r) * 768 + o] = (bf16)(acc[i][j][r] + bj);
      }
    }
  }
}

// ---------------------------------------------------------------------------
// Output projection: out[M,768] fp32 = AO bf16 @ Wo^T + bo (round-7 proven).
// ---------------------------------------------------------------------------
__global__ __launch_bounds__(256)
void gemm_o(const bf16* __restrict__ A, const float* __restrict__ W,
            const float* __restrict__ bias, float* __restrict__ C) {
  constexpr int K = 768;
  __shared__ __align__(16) bf16 As[128 * 32];
  __shared__ __align__(16) bf16 Bs[128 * 32];

  const int tid  = threadIdx.x;
  const int wave = tid >> 6;
  const int lane = tid & 63;
  const int l15  = lane & 15;
  const int q4   = lane >> 4;
  const int wr   = wave >> 1;
  const int wc   = wave & 1;
  const int rb0  = blockIdx.y * 128;
  const int cb0  = blockIdx.x * 128;

  fx4 acc[4][4];
#pragma unroll
  for (int i = 0; i < 4; i++)
#pragma unroll
    for (int j = 0; j < 4; j++) acc[i][j] = (fx4){0.f, 0.f, 0.f, 0.f};

  for (int k0 = 0; k0 < K; k0 += 32) {
    for (int c = tid; c < 512; c += 256) {
      const int row = c >> 2;
      const int kc  = (c & 3) << 3;
      *(uint4*)&As[row * 32 + kc] =
          *(const uint4*)&A[(size_t)(rb0 + row) * K + k0 + kc];
      const float* sb = W + (size_t)(cb0 + row) * K + k0 + kc;
      bf16x8 pb;
#pragma unroll
      for (int t = 0; t < 8; t++) pb[t] = (bf16)sb[t];
      *(bf16x8*)&Bs[row * 32 + kc] = pb;
    }
    __syncthreads();

    bf16x8 a[4], b[4];
#pragma unroll
    for (int i = 0; i < 4; i++)
      a[i] = *(const bf16x8*)&As[(wr * 64 + i * 16 + l15) * 32 + q4 * 8];
#pragma unroll
    for (int j = 0; j < 4; j++)
      b[j] = *(const bf16x8*)&Bs[(wc * 64 + j * 16 + l15) * 32 + q4 * 8];
#pragma unroll
    for (int i = 0; i < 4; i++)
#pragma unroll
      for (int j = 0; j < 4; j++)
        acc[i][j] = MFMA16(a[i], b[j], acc[i][j]);
    __syncthreads();
  }

  const int cb = cb0 + wc * 64;
  const int rb = rb0 + wr * 64;
#pragma unroll
  for (int j = 0; j < 4; j++) {
    const int o  = cb + j * 16 + l15;
    const float bj = bias[o];
#pragma unroll
    for (int i = 0; i < 4; i++) {
      const int r0 = rb + i * 16 + q4 * 4;
#pragma unroll
      for (int r = 0; r < 4; r++)
        C[(size_t)(r0 + r) * 768 + o] = acc[i][j][r] + bj;
    }
  }
}

// ---------------------------------------------------------------------------
// Attention, softmax over HEADS (dim=1), / sqrt(768).
// Round-7 structure EXACTLY (wave=head, TQ=32, grid 256, LDS cross-head
// softmax, 2 barriers/iter) + ONE change: register double-buffer PREFETCH.
// Iteration kt issues kt+1's 12 K/V fragment loads into the alternate
// register set FIRST, so loads are in flight across the whole body
// (QK + scatter + bar + softmax + bar + PV) instead of ~8% of it.
// R7's measured load throughput was ~12 B/cyc/CU (burst-then-idle);
// continuous 12-deep per-wave pipelining should reach L2-limited rates.
// Consuming the current buffer needs no vmcnt wait (disjoint registers);
// only the swap point does. Loop is 2x-unrolled for the A/B buffers.
// +48 VGPRs vs R7 -> still 2 waves/SIMD, same 8 waves/CU occupancy.
// AO aliases Q: block reads only its own 32 Q rows before the loop, writes
// only those rows after it. Ebuf q-stride 260 (2-way scatter: free).
// ---------------------------------------------------------------------------
__global__ __launch_bounds__(512, 2)
void attn_kernel(const bf16* Q, const bf16* __restrict__ Kb,
                 const bf16* __restrict__ Vt, bf16* AO) {
  __shared__ __align__(16) float Ebuf[32 * 260];     // [q][h*32+k], 33.3 KB
  __shared__ __align__(16) bf16  Pbuf[8 * 32 * 32];  // [h][q][k],   16 KB

  const int tid  = threadIdx.x;
  const int h    = tid >> 6;
  const int lane = tid & 63;
  const int l15  = lane & 15;
  const int q4   = lane >> 4;
  const int b    = blockIdx.x >> 6;
  const int qt   = blockIdx.x & 63;
  const int qrow0 = b * 2048 + qt * 32;

  // Persistent Q fragments: 2 q-16tiles x 3 d-chunks.
  bf16x8 aq[2][3];
#pragma unroll
  for (int i = 0; i < 2; i++)
#pragma unroll
    for (int c = 0; c < 3; c++)
      aq[i][c] = *(const bf16x8*)
          &Q[(size_t)(qrow0 + i * 16 + l15) * 768 + h * 96 + c * 32 + q4 * 8];

  fx4 o[2][6];
#pragma unroll
  for (int i = 0; i < 2; i++)
#pragma unroll
    for (int j = 0; j < 6; j++) o[i][j] = (fx4){0.f, 0.f, 0.f, 0.f};

  // Per-lane fixed base pointers.
  const bf16* Kp0 = Kb + (size_t)(b * 2048 + l15) * 768 + h * 96 + q4 * 8;
  const bf16* Vp0 = Vt + (size_t)((b * 8 + h) * 96 + l15) * 2048 + q4 * 8;

  // Double-buffered K/V fragment registers.
  bf16x8 bkA[2][3], bvA[6], bkB[2][3], bvB[6];

  auto loadKV = [&](int kt, bf16x8 (&bk)[2][3], bf16x8 (&bv)[6]) {
    const bf16* Kp = Kp0 + (size_t)(kt * 32) * 768;
#pragma unroll
    for (int j = 0; j < 2; j++)
#pragma unroll
      for (int c = 0; c < 3; c++)
        bk[j][c] = *(const bf16x8*)(Kp + (size_t)(j * 16) * 768 + c * 32);
#pragma unroll
    for (int j2 = 0; j2 < 6; j2++)
      bv[j2] = *(const bf16x8*)(Vp0 + (size_t)(j2 * 16) * 2048 + kt * 32);
  };

  auto body = [&](int kt, bf16x8 (&bk)[2][3], bf16x8 (&bv)[6],
                  bf16x8 (&nk)[2][3], bf16x8 (&nv)[6]) {
    // Prefetch NEXT iteration's fragments first (clamped; last iter re-reads
    // kt=63 harmlessly). These 12 loads stay in flight across the whole body.
    const int kn = (kt + 1 < 64) ? kt + 1 : 63;
    loadKV(kn, nk, nv);

    // E = Q K^T : [32q x 32k] for this head (current regs: no wait needed).
    fx4 e[2][2];
    e[0][0] = e[0][1] = e[1][0] = e[1][1] = (fx4){0.f, 0.f, 0.f, 0.f};
#pragma unroll
    for (int c = 0; c < 3; c++)
#pragma unroll
      for (int j = 0; j < 2; j++) {
        e[0][j] = MFMA16(aq[0][c], bk[j][c], e[0][j]);
        e[1][j] = MFMA16(aq[1][c], bk[j][c], e[1][j]);
      }

    // Scatter E -> Ebuf[q*260 + h*32 + k]
#pragma unroll
    for (int i = 0; i < 2; i++)
#pragma unroll
      for (int j = 0; j < 2; j++)
#pragma unroll
        for (int r = 0; r < 4; r++)
          Ebuf[(i * 16 + q4 * 4 + r) * 260 + h * 32 + j * 16 + l15] =
              e[i][j][r];
    __syncthreads();

    // Softmax over heads. 1024 (q,k) pairs, 2 per thread.
#pragma unroll
    for (int pp = 0; pp < 2; pp++) {
      const int p = tid + pp * 512;
      const int q = p >> 5, k = p & 31;
      float v[8];
#pragma unroll
      for (int hh = 0; hh < 8; hh++) v[hh] = Ebuf[q * 260 + hh * 32 + k];
      float m = v[0];
#pragma unroll
      for (int hh = 1; hh < 8; hh++) m = fmaxf(m, v[hh]);
      float sm = 0.f;
#pragma unroll
      for (int hh = 0; hh < 8; hh++) { v[hh] = __expf(v[hh] - m); sm += v[hh]; }
      const float inv = 1.0f / (sm * 27.712812921102035f);  // / sqrt(768)
#pragma unroll
      for (int hh = 0; hh < 8; hh++)
        Pbuf[hh * 1024 + q * 32 + k] = (bf16)(v[hh] * inv);
    }
    __syncthreads();

    // O += P @ V (V regs from the PREVIOUS iteration's prefetch).
    bf16x8 ap[2];
#pragma unroll
    for (int i = 0; i < 2; i++)
      ap[i] = *(const bf16x8*)&Pbuf[h * 1024 + (i * 16 + l15) * 32 + q4 * 8];
#pragma unroll
    for (int j2 = 0; j2 < 6; j2++) {
      o[0][j2] = MFMA16(ap[0], bv[j2], o[0][j2]);
      o[1][j2] = MFMA16(ap[1], bv[j2], o[1][j2]);
    }
  };

  loadKV(0, bkA, bvA);
  for (int kt = 0; kt < 64; kt += 2) {
    body(kt,     bkA, bvA, bkB, bvB);
    body(kt + 1, bkB, bvB, bkA, bvA);
  }

  // Write AO[qrow0 + q][h*96 + d]
#pragma unroll
  for (int i = 0; i < 2; i++)
#pragma unroll
    for (int j2 = 0; j2 < 6; j2++)
#pragma unroll
      for (int r = 0; r < 4; r++)
        AO[(size_t)(qrow0 + i * 16 + q4 * 4 + r) * 768 + h * 96 + j2 * 16 + l15] =
            (bf16)(o[i][j2][r]);
}

// ---------------------------------------------------------------------------
// Memory plan (proven): d_out = xb + Kw (both dead before gemm_o overwrites
// d_out fp32). ws = Q + Vt (25.2 MB). AO aliases Q.
// ---------------------------------------------------------------------------
extern "C" void kernel_launch(void* const* d_in, const int* in_sizes, int n_in,
                              void* d_out, int out_size, void* d_ws,
                              size_t ws_size, hipStream_t stream) {
  const float* x  = (const float*)d_in[0];
  const float* Wq = (const float*)d_in[1];
  const float* bq = (const float*)d_in[2];
  const float* Wk = (const float*)d_in[3];
  const float* bk = (const float*)d_in[4];
  const float* Wv = (const float*)d_in[5];
  const float* bv = (const float*)d_in[6];
  const float* Wo = (const float*)d_in[7];
  const float* bo = (const float*)d_in[8];

  const size_t MN = (size_t)8192 * 768;
  bf16* xb = (bf16*)d_out;
  bf16* Kw = xb + MN;
  bf16* Q  = (bf16*)d_ws;
  bf16* Vt = Q + MN;
  bf16* AO = Q;  // aliases Q

  cvt_x_kernel<<<6144, 256, 0, stream>>>(x, xb);
  dim3 qkvgrid(18, 64);
  gemm_qkv<<<qkvgrid, 256, 0, stream>>>(xb, Wq, Wk, Wv, bq, bk, bv, Q, Kw, Vt);
  attn_kernel<<<256, 512, 0, stream>>>(Q, Kw, Vt, AO);
  dim3 ogrid(6, 64);
  gemm_o<<<ogrid, 256, 0, stream>>>(AO, Wo, bo, (float*)d_out);
}

// Round 11
// 384.960 us; speedup vs baseline: 1.4106x; 1.0015x over previous
//
#include <hip/hip_runtime.h>

typedef __bf16 bf16;
typedef __bf16 bf16x4 __attribute__((ext_vector_type(4)));
typedef __bf16 bf16x8 __attribute__((ext_vector_type(8)));
typedef float  fx4    __attribute__((ext_vector_type(4)));

#define MFMA16(a, b, c) __builtin_amdgcn_mfma_f32_16x16x32_bf16((a), (b), (c), 0, 0, 0)

// B=4, N=2048, E=768, H=8, D=96; M = B*N = 8192. User tensors fp32, out fp32.

// ---------------------------------------------------------------------------
// Barrier WITHOUT the vmem drain. __syncthreads() emits
// "s_waitcnt vmcnt(0) lgkmcnt(0); s_barrier" — the vmcnt(0) kills register
// prefetch (R10 post-mortem: prefetch was neutral because every barrier
// force-drained it). LDS cross-wave visibility only needs lgkmcnt(0).
// 0xC07F = vmcnt 63 (no wait: bits[3:0]=0xF,[15:14]=3), expcnt 7 (no wait),
// lgkmcnt 0 (bits[11:8]=0). asm memory clobbers stop LLVM reordering
// LDS ops across the barrier.
// ---------------------------------------------------------------------------
__device__ __forceinline__ void barrier_nodrain() {
  __asm__ __volatile__("" ::: "memory");
  __builtin_amdgcn_s_waitcnt(0xC07F);
  __builtin_amdgcn_s_barrier();
  __asm__ __volatile__("" ::: "memory");
}

// ---------------------------------------------------------------------------
// x (fp32) -> bf16, 4 elems/thread.
// ---------------------------------------------------------------------------
__global__ __launch_bounds__(256)
void cvt_x_kernel(const float* __restrict__ x, bf16* __restrict__ xb) {
  const int i = (blockIdx.x * 256 + threadIdx.x) * 4;
  float4 v = *(const float4*)&x[i];
  bf16x4 o;
  o[0] = (bf16)v.x; o[1] = (bf16)v.y; o[2] = (bf16)v.z; o[3] = (bf16)v.w;
  *(bf16x4*)&xb[i] = o;
}

// ---------------------------------------------------------------------------
// Fused QKV GEMM (round-7 proven, untouched). blockIdx.x: 0-5 Q, 6-11 K,
// 12-17 V (transposed out). 1152 blocks. Tile 128x128, BK=32, 4 waves.
// ---------------------------------------------------------------------------
__global__ __launch_bounds__(256)
void gemm_qkv(const bf16* __restrict__ A,
              const float* __restrict__ Wq, const float* __restrict__ Wk,
              const float* __restrict__ Wv,
              const float* __restrict__ bq, const float* __restrict__ bk,
              const float* __restrict__ bv,
              bf16* __restrict__ Qo, bf16* __restrict__ Ko,
              bf16* __restrict__ Vto) {
  constexpr int K = 768;
  __shared__ __align__(16) bf16 As[128 * 32];
  __shared__ __align__(16) bf16 Bs[128 * 32];

  const int tid  = threadIdx.x;
  const int wave = tid >> 6;
  const int lane = tid & 63;
  const int l15  = lane & 15;
  const int q4   = lane >> 4;
  const int wr   = wave >> 1;
  const int wc   = wave & 1;
  const int sel  = blockIdx.x / 6;
  const int cb0  = (blockIdx.x % 6) * 128;
  const int rb0  = blockIdx.y * 128;

  const float* W   = (sel == 0) ? Wq : (sel == 1) ? Wk : Wv;
  const float* bia = (sel == 0) ? bq : (sel == 1) ? bk : bv;

  fx4 acc[4][4];
#pragma unroll
  for (int i = 0; i < 4; i++)
#pragma unroll
    for (int j = 0; j < 4; j++) acc[i][j] = (fx4){0.f, 0.f, 0.f, 0.f};

  for (int k0 = 0; k0 < K; k0 += 32) {
    for (int c = tid; c < 512; c += 256) {
      const int row = c >> 2;
      const int kc  = (c & 3) << 3;
      *(uint4*)&As[row * 32 + kc] =
          *(const uint4*)&A[(size_t)(rb0 + row) * K + k0 + kc];
      const float* sb = W + (size_t)(cb0 + row) * K + k0 + kc;
      bf16x8 pb;
#pragma unroll
      for (int t = 0; t < 8; t++) pb[t] = (bf16)sb[t];
      *(bf16x8*)&Bs[row * 32 + kc] = pb;
    }
    __syncthreads();

    bf16x8 a[4], b[4];
#pragma unroll
    for (int i = 0; i < 4; i++)
      a[i] = *(const bf16x8*)&As[(wr * 64 + i * 16 + l15) * 32 + q4 * 8];
#pragma unroll
    for (int j = 0; j < 4; j++)
      b[j] = *(const bf16x8*)&Bs[(wc * 64 + j * 16 + l15) * 32 + q4 * 8];
#pragma unroll
    for (int i = 0; i < 4; i++)
#pragma unroll
      for (int j = 0; j < 4; j++)
        acc[i][j] = MFMA16(a[i], b[j], acc[i][j]);
    __syncthreads();
  }

  const int cb = cb0 + wc * 64;
  const int rb = rb0 + wr * 64;
  bf16* Co = (sel == 0) ? Qo : Ko;
#pragma unroll
  for (int j = 0; j < 4; j++) {
    const int o  = cb + j * 16 + l15;
    const float bj = bia[o];
#pragma unroll
    for (int i = 0; i < 4; i++) {
      const int r0 = rb + i * 16 + q4 * 4;
      if (sel == 2) {
        const int bb = r0 >> 11;
        const int n0 = r0 & 2047;
        bf16x4 pk;
#pragma unroll
        for (int r = 0; r < 4; r++) pk[r] = (bf16)(acc[i][j][r] + bj);
        *(bf16x4*)&Vto[((size_t)(bb * 768 + o)) * 2048 + n0] = pk;
      } else {
#pragma unroll
        for (int r = 0; r < 4; r++)
          Co[(size_t)(r0 + r) * 768 + o] = (bf16)(acc[i][j][r] + bj);
      }
    }
  }
}

// ---------------------------------------------------------------------------
// Output projection: out[M,768] fp32 = AO bf16 @ Wo^T + bo (untouched).
// ---------------------------------------------------------------------------
__global__ __launch_bounds__(256)
void gemm_o(const bf16* __restrict__ A, const float* __restrict__ W,
            const float* __restrict__ bias, float* __restrict__ C) {
  constexpr int K = 768;
  __shared__ __align__(16) bf16 As[128 * 32];
  __shared__ __align__(16) bf16 Bs[128 * 32];

  const int tid  = threadIdx.x;
  const int wave = tid >> 6;
  const int lane = tid & 63;
  const int l15  = lane & 15;
  const int q4   = lane >> 4;
  const int wr   = wave >> 1;
  const int wc   = wave & 1;
  const int rb0  = blockIdx.y * 128;
  const int cb0  = blockIdx.x * 128;

  fx4 acc[4][4];
#pragma unroll
  for (int i = 0; i < 4; i++)
#pragma unroll
    for (int j = 0; j < 4; j++) acc[i][j] = (fx4){0.f, 0.f, 0.f, 0.f};

  for (int k0 = 0; k0 < K; k0 += 32) {
    for (int c = tid; c < 512; c += 256) {
      const int row = c >> 2;
      const int kc  = (c & 3) << 3;
      *(uint4*)&As[row * 32 + kc] =
          *(const uint4*)&A[(size_t)(rb0 + row) * K + k0 + kc];
      const float* sb = W + (size_t)(cb0 + row) * K + k0 + kc;
      bf16x8 pb;
#pragma unroll
      for (int t = 0; t < 8; t++) pb[t] = (bf16)sb[t];
      *(bf16x8*)&Bs[row * 32 + kc] = pb;
    }
    __syncthreads();

    bf16x8 a[4], b[4];
#pragma unroll
    for (int i = 0; i < 4; i++)
      a[i] = *(const bf16x8*)&As[(wr * 64 + i * 16 + l15) * 32 + q4 * 8];
#pragma unroll
    for (int j = 0; j < 4; j++)
      b[j] = *(const bf16x8*)&Bs[(wc * 64 + j * 16 + l15) * 32 + q4 * 8];
#pragma unroll
    for (int i = 0; i < 4; i++)
#pragma unroll
      for (int j = 0; j < 4; j++)
        acc[i][j] = MFMA16(a[i], b[j], acc[i][j]);
    __syncthreads();
  }

  const int cb = cb0 + wc * 64;
  const int rb = rb0 + wr * 64;
#pragma unroll
  for (int j = 0; j < 4; j++) {
    const int o  = cb + j * 16 + l15;
    const float bj = bias[o];
#pragma unroll
    for (int i = 0; i < 4; i++) {
      const int r0 = rb + i * 16 + q4 * 4;
#pragma unroll
      for (int r = 0; r < 4; r++)
        C[(size_t)(r0 + r) * 768 + o] = acc[i][j][r] + bj;
    }
  }
}

// ---------------------------------------------------------------------------
// Attention, softmax over HEADS (dim=1), / sqrt(768).
// R10 structure (R7 + register double-buffer prefetch) with ONE change:
// both __syncthreads() replaced by barrier_nodrain() (lgkmcnt-only barrier).
// This is what lets the prefetched loads actually stay in flight across the
// whole iteration — __syncthreads' implicit vmcnt(0) was draining them.
// Correctness: identical barrier points; each wave drains its own LDS ops
// (lgkmcnt 0) before s_barrier, so cross-wave LDS visibility is unchanged.
// Prefetched global loads are wave-private (registers) — no cross-wave
// hazard from leaving them outstanding.
// AO aliases Q: block reads only its own 32 Q rows before the loop, writes
// only those rows after it. Ebuf q-stride 260 (2-way scatter: free).
// ---------------------------------------------------------------------------
__global__ __launch_bounds__(512, 2)
void attn_kernel(const bf16* Q, const bf16* __restrict__ Kb,
                 const bf16* __restrict__ Vt, bf16* AO) {
  __shared__ __align__(16) float Ebuf[32 * 260];     // [q][h*32+k], 33.3 KB
  __shared__ __align__(16) bf16  Pbuf[8 * 32 * 32];  // [h][q][k],   16 KB

  const int tid  = threadIdx.x;
  const int h    = tid >> 6;
  const int lane = tid & 63;
  const int l15  = lane & 15;
  const int q4   = lane >> 4;
  const int b    = blockIdx.x >> 6;
  const int qt   = blockIdx.x & 63;
  const int qrow0 = b * 2048 + qt * 32;

  // Persistent Q fragments: 2 q-16tiles x 3 d-chunks.
  bf16x8 aq[2][3];
#pragma unroll
  for (int i = 0; i < 2; i++)
#pragma unroll
    for (int c = 0; c < 3; c++)
      aq[i][c] = *(const bf16x8*)
          &Q[(size_t)(qrow0 + i * 16 + l15) * 768 + h * 96 + c * 32 + q4 * 8];

  fx4 o[2][6];
#pragma unroll
  for (int i = 0; i < 2; i++)
#pragma unroll
    for (int j = 0; j < 6; j++) o[i][j] = (fx4){0.f, 0.f, 0.f, 0.f};

  // Per-lane fixed base pointers.
  const bf16* Kp0 = Kb + (size_t)(b * 2048 + l15) * 768 + h * 96 + q4 * 8;
  const bf16* Vp0 = Vt + (size_t)((b * 8 + h) * 96 + l15) * 2048 + q4 * 8;

  // Double-buffered K/V fragment registers.
  bf16x8 bkA[2][3], bvA[6], bkB[2][3], bvB[6];

  auto loadKV = [&](int kt, bf16x8 (&bk)[2][3], bf16x8 (&bv)[6]) {
    const bf16* Kp = Kp0 + (size_t)(kt * 32) * 768;
#pragma unroll
    for (int j = 0; j < 2; j++)
#pragma unroll
      for (int c = 0; c < 3; c++)
        bk[j][c] = *(const bf16x8*)(Kp + (size_t)(j * 16) * 768 + c * 32);
#pragma unroll
    for (int j2 = 0; j2 < 6; j2++)
      bv[j2] = *(const bf16x8*)(Vp0 + (size_t)(j2 * 16) * 2048 + kt * 32);
  };

  auto body = [&](int kt, bf16x8 (&bk)[2][3], bf16x8 (&bv)[6],
                  bf16x8 (&nk)[2][3], bf16x8 (&nv)[6]) {
    // Prefetch NEXT iteration's fragments (stay in flight across the whole
    // body now that barriers don't drain vmcnt).
    const int kn = (kt + 1 < 64) ? kt + 1 : 63;
    loadKV(kn, nk, nv);

    // E = Q K^T : [32q x 32k] for this head (current regs, loaded last iter).
    fx4 e[2][2];
    e[0][0] = e[0][1] = e[1][0] = e[1][1] = (fx4){0.f, 0.f, 0.f, 0.f};
#pragma unroll
    for (int c = 0; c < 3; c++)
#pragma unroll
      for (int j = 0; j < 2; j++) {
        e[0][j] = MFMA16(aq[0][c], bk[j][c], e[0][j]);
        e[1][j] = MFMA16(aq[1][c], bk[j][c], e[1][j]);
      }

    // Scatter E -> Ebuf[q*260 + h*32 + k]
#pragma unroll
    for (int i = 0; i < 2; i++)
#pragma unroll
      for (int j = 0; j < 2; j++)
#pragma unroll
        for (int r = 0; r < 4; r++)
          Ebuf[(i * 16 + q4 * 4 + r) * 260 + h * 32 + j * 16 + l15] =
              e[i][j][r];
    barrier_nodrain();

    // Softmax over heads. 1024 (q,k) pairs, 2 per thread.
#pragma unroll
    for (int pp = 0; pp < 2; pp++) {
      const int p = tid + pp * 512;
      const int q = p >> 5, k = p & 31;
      float v[8];
#pragma unroll
      for (int hh = 0; hh < 8; hh++) v[hh] = Ebuf[q * 260 + hh * 32 + k];
      float m = v[0];
#pragma unroll
      for (int hh = 1; hh < 8; hh++) m = fmaxf(m, v[hh]);
      float sm = 0.f;
#pragma unroll
      for (int hh = 0; hh < 8; hh++) { v[hh] = __expf(v[hh] - m); sm += v[hh]; }
      const float inv = 1.0f / (sm * 27.712812921102035f);  // / sqrt(768)
#pragma unroll
      for (int hh = 0; hh < 8; hh++)
        Pbuf[hh * 1024 + q * 32 + k] = (bf16)(v[hh] * inv);
    }
    barrier_nodrain();

    // O += P @ V (V regs from the previous iteration's prefetch).
    bf16x8 ap[2];
#pragma unroll
    for (int i = 0; i < 2; i++)
      ap[i] = *(const bf16x8*)&Pbuf[h * 1024 + (i * 16 + l15) * 32 + q4 * 8];
#pragma unroll
    for (int j2 = 0; j2 < 6; j2++) {
      o[0][j2] = MFMA16(ap[0], bv[j2], o[0][j2]);
      o[1][j2] = MFMA16(ap[1], bv[j2], o[1][j2]);
    }
  };

  loadKV(0, bkA, bvA);
  for (int kt = 0; kt < 64; kt += 2) {
    body(kt,     bkA, bvA, bkB, bvB);
    body(kt + 1, bkB, bvB, bkA, bvA);
  }

  // Write AO[qrow0 + q][h*96 + d]
#pragma unroll
  for (int i = 0; i < 2; i++)
#pragma unroll
    for (int j2 = 0; j2 < 6; j2++)
#pragma unroll
      for (int r = 0; r < 4; r++)
        AO[(size_t)(qrow0 + i * 16 + q4 * 4 + r) * 768 + h * 96 + j2 * 16 + l15] =
            (bf16)(o[i][j2][r]);
}

// ---------------------------------------------------------------------------
// Memory plan (proven): d_out = xb + Kw (both dead before gemm_o overwrites
// d_out fp32). ws = Q + Vt (25.2 MB). AO aliases Q.
// ---------------------------------------------------------------------------
extern "C" void kernel_launch(void* const* d_in, const int* in_sizes, int n_in,
                              void* d_out, int out_size, void* d_ws,
                              size_t ws_size, hipStream_t stream) {
  const float* x  = (const float*)d_in[0];
  const float* Wq = (const float*)d_in[1];
  const float* bq = (const float*)d_in[2];
  const float* Wk = (const float*)d_in[3];
  const float* bk = (const float*)d_in[4];
  const float* Wv = (const float*)d_in[5];
  const float* bv = (const float*)d_in[6];
  const float* Wo = (const float*)d_in[7];
  const float* bo = (const float*)d_in[8];

  const size_t MN = (size_t)8192 * 768;
  bf16* xb = (bf16*)d_out;
  bf16* Kw = xb + MN;
  bf16* Q  = (bf16*)d_ws;
  bf16* Vt = Q + MN;
  bf16* AO = Q;  // aliases Q

  cvt_x_kernel<<<6144, 256, 0, stream>>>(x, xb);
  dim3 qkvgrid(18, 64);
  gemm_qkv<<<qkvgrid, 256, 0, stream>>>(xb, Wq, Wk, Wv, bq, bk, bv, Q, Kw, Vt);
  attn_kernel<<<256, 512, 0, stream>>>(Q, Kw, Vt, AO);
  dim3 ogrid(6, 64);
  gemm_o<<<ogrid, 256, 0, stream>>>(AO, Wo, bo, (float*)d_out);
}